// Round 7
// baseline (1007.854 us; speedup 1.0000x reference)
//
#include <hip/hip_runtime.h>
#include <math.h>

#define DIM   512
#define CDIM  128
#define CSIZE 8192
#define NTOK  16384          // 4 * 4096
#define EPSV  1e-6f
#define NSLICE 8             // k_dist grid.y code slices
#define NSLICE2 16           // effective output slices (each col-half wave owns one)

#define SELU_SCALE 1.0507009873554805f
#define SELU_ALPHA 1.6732632423543772f

typedef __bf16 bf16x8 __attribute__((ext_vector_type(8)));
typedef float  f32x4  __attribute__((ext_vector_type(4)));
typedef unsigned short u16x8 __attribute__((ext_vector_type(8)));

__device__ __forceinline__ float selu_f(float v) {
    return SELU_SCALE * (v > 0.f ? v : SELU_ALPHA * expm1f(v));
}

// RNE float -> bf16 bits
__device__ __forceinline__ unsigned short b16(float f) {
    unsigned u = __float_as_uint(f);
    u += 0x7FFFu + ((u >> 16) & 1u);
    return (unsigned short)(u >> 16);
}
__device__ __forceinline__ float b2f(unsigned short h) {
    return __uint_as_float(((unsigned)h) << 16);
}

// LDS byte-swizzle involution (verified 0 bank conflicts, rounds 3-6)
__device__ __forceinline__ unsigned SWZ(unsigned b) {
    return b ^ (((b >> 6) & 14u) << 3);
}

#define GLOAD16(g, l) __builtin_amdgcn_global_load_lds( \
    (const __attribute__((address_space(1))) void*)(g),  \
    (__attribute__((address_space(3))) void*)(l), 16, 0, 0)

// ---------------------------------------------------------------- init / fin
__global__ __launch_bounds__(256) void k_init(float* __restrict__ rn2,
                                              float* __restrict__ lossacc) {
    const int i = blockIdx.x * 256 + threadIdx.x;
    if (i < CSIZE) rn2[i] = 0.f;
    if (i < 64)    lossacc[i] = 0.f;
}

__global__ void k_fin(const float* __restrict__ lossacc, float* __restrict__ out_loss) {
    float v = lossacc[threadIdx.x];   // 64 threads
#pragma unroll
    for (int o = 1; o < 64; o <<= 1) v += __shfl_xor(v, o);
    if (threadIdx.x == 0)
        out_loss[0] = 1.25f * v / (float)((size_t)NTOK * DIM);
}

// ---------------------------------------------------------------- split f32 -> bf16 hi/lo (x)
__global__ __launch_bounds__(256) void k_split(const float* __restrict__ in,
                                               unsigned short* __restrict__ hi,
                                               unsigned short* __restrict__ lo,
                                               int n4) {
    const int i = blockIdx.x * 256 + threadIdx.x;
    if (i >= n4) return;
    const float4 v = ((const float4*)in)[i];
    const unsigned short h0 = b16(v.x), h1 = b16(v.y), h2 = b16(v.z), h3 = b16(v.w);
    const unsigned short l0 = b16(v.x - b2f(h0));
    const unsigned short l1 = b16(v.y - b2f(h1));
    const unsigned short l2 = b16(v.z - b2f(h2));
    const unsigned short l3 = b16(v.w - b2f(h3));
    ((ushort4*)hi)[i] = make_ushort4(h0, h1, h2, h3);
    ((ushort4*)lo)[i] = make_ushort4(l0, l1, l2, l3);
}

// ---------------------------------------------------------------- transpose + split: W[K,N] -> WT hi/lo [N,K]
__global__ __launch_bounds__(256) void k_splitT(const float* __restrict__ W,
                                                unsigned short* __restrict__ Thi,
                                                unsigned short* __restrict__ Tlo,
                                                int K, int N) {
    __shared__ float t[32][33];
    const int tx = threadIdx.x & 31, ty = threadIdx.x >> 5;   // 32 x 8
    const int n0 = blockIdx.x * 32, k0 = blockIdx.y * 32;
#pragma unroll
    for (int i = 0; i < 4; ++i)
        t[ty + i * 8][tx] = W[(size_t)(k0 + ty + i * 8) * N + n0 + tx];
    __syncthreads();
#pragma unroll
    for (int i = 0; i < 4; ++i) {
        const int n = n0 + ty + i * 8, k = k0 + tx;
        const float v = t[tx][ty + i * 8];
        const unsigned short h = b16(v);
        Thi[(size_t)n * K + k] = h;
        Tlo[(size_t)n * K + k] = b16(v - b2f(h));
    }
}

// ---------------------------------------------------------------- MFMA GEMM (split-bf16, 3-term)
// Tile 128(m) x 64(n), 4 waves of 64x32. A reg-staged (f32 -> selu? -> split ->
// swizzled ds_write); B via gload_lds (linear dest + SWZ source); reads SWZ'd.
// OUT_SPLIT=false: out = acc + bias (f32, gemm1 -> h).
// OUT_SPLIT=true : v = acc + bias + res; emit split bf16 hi/lo + rn2 atomics (gemm2).
template<int KTOT, bool OUT_SPLIT>
__global__ __launch_bounds__(256) void k_gemm(const float* __restrict__ A,
                                              const unsigned short* __restrict__ BThi,
                                              const unsigned short* __restrict__ BTlo,
                                              const float* __restrict__ bias,
                                              const float* __restrict__ res,
                                              float* __restrict__ outF,
                                              unsigned short* __restrict__ outHi,
                                              unsigned short* __restrict__ outLo,
                                              float* __restrict__ rn2) {
    __shared__ __align__(16) unsigned char smem[24576];   // AH 8K | AL 8K | BH 4K | BL 4K
    const int tid = threadIdx.x;
    const int wave = tid >> 6, lane = tid & 63;
    const int l15 = lane & 15, l4 = lane >> 4;
    const int m0 = blockIdx.x * 128, n0 = blockIdx.y * 64;
    const int wm0 = (wave >> 1) * 64, wn0 = (wave & 1) * 32;

    // B staging source offset (4KB tile, one round: chunk p = tid*16)
    const unsigned LB = SWZ((unsigned)tid * 16u);
    const int soffB = (int)(LB >> 6) * KTOT + (int)((LB >> 4) & 3) * 8;

    // fragment read offsets (mi/ni stride +1024)
    const unsigned ra0 = SWZ((unsigned)((wm0 + l15) * 64 + l4 * 16));
    const unsigned rb0 = SWZ((unsigned)((wn0 + l15) * 64 + l4 * 16));

    f32x4 acc[4][2];
#pragma unroll
    for (int a = 0; a < 4; ++a)
#pragma unroll
        for (int b = 0; b < 2; ++b) acc[a][b] = (f32x4)(0.f);

    for (int k0 = 0; k0 < KTOT; k0 += 32) {
        __syncthreads();
        // B: global_load_lds, linear dest (wave w covers bytes [w*1024,(w+1)*1024))
        GLOAD16(BThi + (size_t)n0 * KTOT + k0 + soffB, smem + 16384 + wave * 1024);
        GLOAD16(BTlo + (size_t)n0 * KTOT + k0 + soffB, smem + 20480 + wave * 1024);
        // A: reg-stage f32 -> (selu) -> split -> ds_write at SWZ(linear)
#pragma unroll
        for (int r = 0; r < 2; ++r) {
            const unsigned g = (unsigned)(tid + r * 256) * 16u;   // byte in [128][64B]
            const int grow = (int)(g >> 6), gel = (int)((g >> 4) & 3) * 8;
            const float4 v0 = *(const float4*)(A + (size_t)(m0 + grow) * KTOT + k0 + gel);
            const float4 v1 = *(const float4*)(A + (size_t)(m0 + grow) * KTOT + k0 + gel + 4);
            float s[8] = {v0.x, v0.y, v0.z, v0.w, v1.x, v1.y, v1.z, v1.w};
            u16x8 hv, lv;
#pragma unroll
            for (int j = 0; j < 8; ++j) {
                const float sv = OUT_SPLIT ? selu_f(s[j]) : s[j];
                const unsigned short hb = b16(sv);
                hv[j] = hb;
                lv[j] = b16(sv - b2f(hb));
            }
            const unsigned d = SWZ(g);
            *(u16x8*)(smem + d) = hv;
            *(u16x8*)(smem + 8192 + d) = lv;
        }
        __syncthreads();

        bf16x8 bh[2], bl[2];
#pragma unroll
        for (int ni = 0; ni < 2; ++ni) {
            bh[ni] = *(const bf16x8*)(smem + 16384 + rb0 + ni * 1024);
            bl[ni] = *(const bf16x8*)(smem + 20480 + rb0 + ni * 1024);
        }
#pragma unroll
        for (int mi = 0; mi < 4; ++mi) {
            const bf16x8 ah = *(const bf16x8*)(smem + ra0 + mi * 1024);
            const bf16x8 al = *(const bf16x8*)(smem + 8192 + ra0 + mi * 1024);
#pragma unroll
            for (int ni = 0; ni < 2; ++ni) {
                acc[mi][ni] = __builtin_amdgcn_mfma_f32_16x16x32_bf16(ah, bh[ni], acc[mi][ni], 0, 0, 0);
                acc[mi][ni] = __builtin_amdgcn_mfma_f32_16x16x32_bf16(ah, bl[ni], acc[mi][ni], 0, 0, 0);
                acc[mi][ni] = __builtin_amdgcn_mfma_f32_16x16x32_bf16(al, bh[ni], acc[mi][ni], 0, 0, 0);
            }
        }
    }
    // epilogue: C layout col = lane&15, row = (lane>>4)*4 + reg
#pragma unroll
    for (int mi = 0; mi < 4; ++mi)
#pragma unroll
        for (int rr = 0; rr < 4; ++rr) {
            const int m = m0 + wm0 + mi * 16 + l4 * 4 + rr;
            float s2 = 0.f;
#pragma unroll
            for (int ni = 0; ni < 2; ++ni) {
                const int n = n0 + wn0 + ni * 16 + l15;
                float v = acc[mi][ni][rr] + bias[n];
                if constexpr (OUT_SPLIT) {
                    v += res[(size_t)m * DIM + n];
                    const unsigned short hb = b16(v);
                    outHi[(size_t)m * DIM + n] = hb;
                    outLo[(size_t)m * DIM + n] = b16(v - b2f(hb));
                    s2 = fmaf(v, v, s2);
                } else {
                    outF[(size_t)m * DIM + n] = v;
                }
            }
            if constexpr (OUT_SPLIT) {
#pragma unroll
                for (int o = 1; o < 16; o <<= 1) s2 += __shfl_xor(s2, o);
                if (l15 == 0) atomicAdd(&rn2[m], s2);
            }
        }
}

// ---------------------------------------------------------------- MFMA distance + partial argmin
// Block: 128 tokens x 1024 codes (4 n-tiles of 256). 256 thr = 4 waves (2m x 2n),
// wave tile 64 tok x 128 codes. B (codes) in LDS dbuf 2x32KB; A (tokens) read
// DIRECTLY global->register (contiguous 16B per lane), prefetched one K-step
// ahead into the opposite parity reg set (pre-barrier vmcnt drain = arrival).
// 64KB LDS -> 2 blocks/CU resident: cross-block desync hides barrier drains.
// One __syncthreads per K-step (race-free: buf overwritten was consumed before
// the PREVIOUS barrier). d2' = rn2[c] - 2*(xh.ch + xh.cl + xl.ch).
// Each col-half wave owns output slice = blockIdx.y*2 + (wave&1): one writer/slot.
__global__ __launch_bounds__(256, 2) void k_dist(const unsigned short* __restrict__ xh,
                                                 const unsigned short* __restrict__ xl,
                                                 const unsigned short* __restrict__ ch,
                                                 const unsigned short* __restrict__ cl,
                                                 const float* __restrict__ rn2,
                                                 float* __restrict__ pval,
                                                 int*   __restrict__ pidx) {
    __shared__ __align__(16) unsigned char smem[65536];   // {CH 16K | CL 16K} x 2
    const int tid  = threadIdx.x;
    const int wave = tid >> 6, lane = tid & 63;
    const int l15 = lane & 15, l4 = lane >> 4;
    const int m0   = blockIdx.x * 128;
    const int wm0  = (wave >> 1) * 64;     // token rows (2 m-waves)
    const int wn0  = (wave & 1) * 128;     // code cols (2 col-half waves)

    // B staging source offset: chunk p = (tid + r*256)*16; SWZ mask r-invariant
    const unsigned LS = SWZ((unsigned)tid * 16u);
    const int soff0 = (int)(LS >> 6) * DIM + (int)((LS >> 4) & 3) * 8;

    // B fragment read offset (ni stride +1024; SWZ mask ni-invariant)
    const unsigned rb0 = SWZ((unsigned)((wn0 + l15) * 64 + l4 * 16));

    // A per-lane base: token row wm0 + f*16 + l15, k-slice l4*8 (16B contiguous)
    const unsigned short* xhb = xh + (size_t)(m0 + wm0 + l15) * DIM + l4 * 8;
    const unsigned short* xlb = xl + (size_t)(m0 + wm0 + l15) * DIM + l4 * 8;

    const int cbase = blockIdx.y * (CSIZE / NSLICE);
    constexpr int NT   = (CSIZE / NSLICE) / 256;   // 4 n-tiles
    constexpr int TOTI = NT * 16;                  // 64 K-step iterations

    auto stageB = [&](int it, unsigned bufbase) {
        const size_t cb0 = (size_t)(cbase + (it >> 4) * 256) * DIM + (it & 15) * 32 + soff0;
#pragma unroll
        for (int r = 0; r < 4; ++r) {
            GLOAD16(ch + cb0 + r * 64 * DIM, smem + bufbase + 0     + r * 4096 + wave * 1024);
            GLOAD16(cl + cb0 + r * 64 * DIM, smem + bufbase + 16384 + r * 4096 + wave * 1024);
        }
    };

    bf16x8 aH[2][4], aL[2][4];
    auto loadA = [&](int it, int par) {
        const int k0 = (it & 15) * 32;
#pragma unroll
        for (int f = 0; f < 4; ++f) {
            aH[par][f] = *(const bf16x8*)(xhb + (size_t)f * 16 * DIM + k0);
            aL[par][f] = *(const bf16x8*)(xlb + (size_t)f * 16 * DIM + k0);
        }
    };

    float bestv[4][4];
    int   besti[4][4];
#pragma unroll
    for (int a = 0; a < 4; ++a)
#pragma unroll
        for (int b = 0; b < 4; ++b) { bestv[a][b] = 3.0e38f; besti[a][b] = 0; }

    // prologue
    stageB(0, 0u);
    loadA(0, 0);
    __syncthreads();
    unsigned cur = 0;

    for (int nt = 0; nt < NT; ++nt) {
        f32x4 acc[4][8];
#pragma unroll
        for (int a = 0; a < 4; ++a)
#pragma unroll
            for (int b = 0; b < 8; ++b) acc[a][b] = (f32x4)(0.f);

#pragma unroll
        for (int ks = 0; ks < 16; ++ks) {
            const int it = nt * 16 + ks;
            if (it + 1 < TOTI) {
                stageB(it + 1, (cur ^ 1u) * 32768u);
                loadA(it + 1, (ks + 1) & 1);     // static parity (full unroll)
            }
            const unsigned char* base = smem + cur * 32768u;
            __builtin_amdgcn_s_setprio(1);
#pragma unroll
            for (int ni = 0; ni < 8; ++ni) {
                const bf16x8 bh = *(const bf16x8*)(base + rb0 + ni * 1024);
                const bf16x8 bl = *(const bf16x8*)(base + 16384 + rb0 + ni * 1024);
#pragma unroll
                for (int mi = 0; mi < 4; ++mi) {
                    acc[mi][ni] = __builtin_amdgcn_mfma_f32_16x16x32_bf16(aH[ks & 1][mi], bh, acc[mi][ni], 0, 0, 0);
                    acc[mi][ni] = __builtin_amdgcn_mfma_f32_16x16x32_bf16(aH[ks & 1][mi], bl, acc[mi][ni], 0, 0, 0);
                    acc[mi][ni] = __builtin_amdgcn_mfma_f32_16x16x32_bf16(aL[ks & 1][mi], bh, acc[mi][ni], 0, 0, 0);
                }
            }
            __builtin_amdgcn_s_setprio(0);
            __syncthreads();   // drains this iter's stage + A prefetch; next buf ready
            cur ^= 1u;
        }

        // fold this n-tile into per-lane running best (d2 minus ||x||^2 const)
        const int n0 = cbase + nt * 256;
#pragma unroll
        for (int ni = 0; ni < 8; ++ni) {
            const int n = n0 + wn0 + ni * 16 + l15;
            const float r = rn2[n];
#pragma unroll
            for (int mi = 0; mi < 4; ++mi)
#pragma unroll
                for (int rr = 0; rr < 4; ++rr) {
                    const float v = fmaf(-2.f, acc[mi][ni][rr], r);
                    if (v < bestv[mi][rr]) { bestv[mi][rr] = v; besti[mi][rr] = n; }
                }
        }
    }

    // reduce across 16 column-lanes; each col-half wave owns its slice
    const int slice = blockIdx.y * 2 + (wave & 1);
#pragma unroll
    for (int mi = 0; mi < 4; ++mi)
#pragma unroll
        for (int rr = 0; rr < 4; ++rr) {
            float v = bestv[mi][rr];
            int   id = besti[mi][rr];
#pragma unroll
            for (int o = 1; o < 16; o <<= 1) {
                const float ov = __shfl_xor(v, o);
                const int   oid = __shfl_xor(id, o);
                if (ov < v || (ov == v && oid < id)) { v = ov; id = oid; }
            }
            if (l15 == 0) {
                const int m = m0 + wm0 + mi * 16 + l4 * 4 + rr;
                pval[(size_t)slice * NTOK + m] = v;
                pidx[(size_t)slice * NTOK + m] = id;
            }
        }
}

// ---------------------------------------------------------------- epilogue: argmin, gather(reconstruct), rotate, loss
// 4 tokens per block, one wave per token. Loss into 64 distributed slots.
__global__ __launch_bounds__(256) void k_epi(const float* __restrict__ x,
                                             const unsigned short* __restrict__ chi,
                                             const unsigned short* __restrict__ clo,
                                             const float* __restrict__ pval,
                                             const int*   __restrict__ pidx,
                                             float* __restrict__ out_q,
                                             float* __restrict__ out_idx,
                                             float* __restrict__ lossacc) {
    const int wave = threadIdx.x >> 6, lane = threadIdx.x & 63;
    const int t = blockIdx.x * 4 + wave;

    float v = 3.0e38f; int id = 0;
    if (lane < NSLICE2) {
        v  = pval[(size_t)lane * NTOK + t];
        id = pidx[(size_t)lane * NTOK + t];
    }
#pragma unroll
    for (int o = 1; o < 16; o <<= 1) {
        const float ov = __shfl_xor(v, o);
        const int   oid = __shfl_xor(id, o);
        if (ov < v || (ov == v && oid < id)) { v = ov; id = oid; }
    }
    id = __shfl(id, 0);

    const float4* xp = (const float4*)(x + (size_t)t * DIM);
    const float4 xv0 = xp[lane * 2];
    const float4 xv1 = xp[lane * 2 + 1];
    const u16x8 hv = *(const u16x8*)(chi + (size_t)id * DIM + lane * 8);
    const u16x8 lv = *(const u16x8*)(clo + (size_t)id * DIM + lane * 8);
    float q[8], xs[8] = {xv0.x, xv0.y, xv0.z, xv0.w, xv1.x, xv1.y, xv1.z, xv1.w};
#pragma unroll
    for (int j = 0; j < 8; ++j) q[j] = b2f(hv[j]) + b2f(lv[j]);

    float p0 = 0.f, p1 = 0.f, p2 = 0.f;
#pragma unroll
    for (int j = 0; j < 8; ++j) {
        p0 = fmaf(xs[j], xs[j], p0);
        p1 = fmaf(q[j], q[j], p1);
        p2 = fmaf(xs[j], q[j], p2);
    }
#pragma unroll
    for (int o = 1; o < 64; o <<= 1) {
        p0 += __shfl_xor(p0, o);
        p1 += __shfl_xor(p1, o);
        p2 += __shfl_xor(p2, o);
    }
    const float sx2 = p0, sq2 = p1, sxq = p2;

    const float ns  = sqrtf(sx2);
    const float nt  = sqrtf(sq2);
    const float nsc = fmaxf(ns, EPSV);
    const float ntc = fmaxf(nt, EPSV);
    const float xu  = sx2 / nsc;
    const float xqh = sxq / ntc;
    const float xw0 = xu + xqh;
    const float w0n2 = sx2 / (nsc * nsc) + 2.f * sxq / (nsc * ntc) + sq2 / (ntc * ntc);
    const float w0nc = fmaxf(sqrtf(w0n2), EPSV);
    const float coefW = 2.f * xw0 / (w0nc * w0nc);
    const float coefQ = 2.f * xu / ntc;
    const float scale = nt / nsc;
    const float cx = scale * (1.f - coefW / nsc);
    const float cq = scale * (coefQ - coefW / ntc);

    float4 ov0, ov1;
    ov0.x = cx * xs[0] + cq * q[0];  ov0.y = cx * xs[1] + cq * q[1];
    ov0.z = cx * xs[2] + cq * q[2];  ov0.w = cx * xs[3] + cq * q[3];
    ov1.x = cx * xs[4] + cq * q[4];  ov1.y = cx * xs[5] + cq * q[5];
    ov1.z = cx * xs[6] + cq * q[6];  ov1.w = cx * xs[7] + cq * q[7];
    ((float4*)(out_q + (size_t)t * DIM))[lane * 2]     = ov0;
    ((float4*)(out_q + (size_t)t * DIM))[lane * 2 + 1] = ov1;

    __shared__ float sew[4];
    if (lane == 0) {
        out_idx[t] = (float)id;
        sew[wave] = sx2 - 2.f * sxq + sq2;
    }
    __syncthreads();
    if (threadIdx.x == 0) {
        const float se = sew[0] + sew[1] + sew[2] + sew[3];
        atomicAdd(lossacc + (blockIdx.x & 63), se);
    }
}

// ---------------------------------------------------------------- launch
extern "C" void kernel_launch(void* const* d_in, const int* in_sizes, int n_in,
                              void* d_out, int out_size, void* d_ws, size_t ws_size,
                              hipStream_t stream) {
    const float* x  = (const float*)d_in[0];
    const float* cb = (const float*)d_in[1];
    const float* W1 = (const float*)d_in[2];
    const float* b1 = (const float*)d_in[3];
    const float* W2 = (const float*)d_in[4];
    const float* b2 = (const float*)d_in[5];

    char* ws = (char*)d_ws;
    float* h = (float*)ws;                                         // 16.78 MB (gemm1 out)
    unsigned short* chi = (unsigned short*)(h + (size_t)CSIZE * DIM);   // 8.39 MB
    unsigned short* clo = chi + (size_t)CSIZE * DIM;               // 8.39 MB
    unsigned short* W1Thi = clo + (size_t)CSIZE * DIM;
    unsigned short* W1Tlo = W1Thi + (size_t)DIM * CDIM;
    unsigned short* W2Thi = W1Tlo + (size_t)DIM * CDIM;
    unsigned short* W2Tlo = W2Thi + (size_t)DIM * DIM;
    float* rn2  = (float*)(W2Tlo + (size_t)DIM * DIM);             // 32 KB
    float* pval = rn2 + CSIZE;                                     // 16*NTOK f32
    int*   pidx = (int*)(pval + (size_t)NSLICE2 * NTOK);           // 16*NTOK i32
    float* lossacc = (float*)(pidx + (size_t)NSLICE2 * NTOK);      // 64 f32

    // x splits overlay d_out's out_q region (dead until k_epi writes it)
    unsigned short* xhi = (unsigned short*)d_out;
    unsigned short* xlo = xhi + (size_t)NTOK * DIM;

    float* out_q    = (float*)d_out;
    float* out_idx  = out_q + (size_t)NTOK * DIM;
    float* out_loss = out_idx + NTOK;

    k_init<<<(CSIZE + 255) / 256, 256, 0, stream>>>(rn2, lossacc);
    k_split<<<(NTOK * DIM / 4) / 256, 256, 0, stream>>>(x, xhi, xlo, NTOK * DIM / 4);
    k_splitT<<<dim3(DIM / 32, CDIM / 32), 256, 0, stream>>>(W1, W1Thi, W1Tlo, CDIM, DIM);
    k_splitT<<<dim3(DIM / 32, DIM / 32), 256, 0, stream>>>(W2, W2Thi, W2Tlo, DIM, DIM);
    k_gemm<CDIM, false><<<dim3(CSIZE / 128, DIM / 64), 256, 0, stream>>>(
        cb, W1Thi, W1Tlo, b1, nullptr, h, nullptr, nullptr, nullptr);
    k_gemm<DIM, true><<<dim3(CSIZE / 128, DIM / 64), 256, 0, stream>>>(
        h, W2Thi, W2Tlo, b2, h, nullptr, chi, clo, rn2);
    k_dist<<<dim3(NTOK / 128, NSLICE), 256, 0, stream>>>(xhi, xlo, chi, clo, rn2, pval, pidx);
    k_epi<<<NTOK / 4, 256, 0, stream>>>(x, chi, clo, pval, pidx, out_q, out_idx, lossacc);
    k_fin<<<1, 64, 0, stream>>>(lossacc, out_loss);
}

// Round 8
// 771.078 us; speedup vs baseline: 1.3071x; 1.3071x over previous
//
#include <hip/hip_runtime.h>
#include <math.h>

#define DIM   512
#define CDIM  128
#define CSIZE 8192
#define NTOK  16384          // 4 * 4096
#define EPSV  1e-6f
#define NSLICE 8             // k_dist grid.y code slices
#define NSLICE2 16           // effective output slices (each col-half wave owns one)

#define SELU_SCALE 1.0507009873554805f
#define SELU_ALPHA 1.6732632423543772f

typedef __bf16 bf16x8 __attribute__((ext_vector_type(8)));
typedef float  f32x4  __attribute__((ext_vector_type(4)));
typedef unsigned short u16x8 __attribute__((ext_vector_type(8)));

__device__ __forceinline__ float selu_f(float v) {
    return SELU_SCALE * (v > 0.f ? v : SELU_ALPHA * expm1f(v));
}

// RNE float -> bf16 bits
__device__ __forceinline__ unsigned short b16(float f) {
    unsigned u = __float_as_uint(f);
    u += 0x7FFFu + ((u >> 16) & 1u);
    return (unsigned short)(u >> 16);
}
__device__ __forceinline__ float b2f(unsigned short h) {
    return __uint_as_float(((unsigned)h) << 16);
}

// LDS byte-swizzle involution (verified 0 bank conflicts, rounds 3-7)
__device__ __forceinline__ unsigned SWZ(unsigned b) {
    return b ^ (((b >> 6) & 14u) << 3);
}

#define GLOAD16(g, l) __builtin_amdgcn_global_load_lds( \
    (const __attribute__((address_space(1))) void*)(g),  \
    (__attribute__((address_space(3))) void*)(l), 16, 0, 0)

// ---------------------------------------------------------------- init / fin
__global__ __launch_bounds__(256) void k_init(float* __restrict__ rn2,
                                              float* __restrict__ lossacc) {
    const int i = blockIdx.x * 256 + threadIdx.x;
    if (i < CSIZE) rn2[i] = 0.f;
    if (i < 64)    lossacc[i] = 0.f;
}

__global__ void k_fin(const float* __restrict__ lossacc, float* __restrict__ out_loss) {
    float v = lossacc[threadIdx.x];   // 64 threads
#pragma unroll
    for (int o = 1; o < 64; o <<= 1) v += __shfl_xor(v, o);
    if (threadIdx.x == 0)
        out_loss[0] = 1.25f * v / (float)((size_t)NTOK * DIM);
}

// ---------------------------------------------------------------- split f32 -> bf16 hi/lo (x)
__global__ __launch_bounds__(256) void k_split(const float* __restrict__ in,
                                               unsigned short* __restrict__ hi,
                                               unsigned short* __restrict__ lo,
                                               int n4) {
    const int i = blockIdx.x * 256 + threadIdx.x;
    if (i >= n4) return;
    const float4 v = ((const float4*)in)[i];
    const unsigned short h0 = b16(v.x), h1 = b16(v.y), h2 = b16(v.z), h3 = b16(v.w);
    const unsigned short l0 = b16(v.x - b2f(h0));
    const unsigned short l1 = b16(v.y - b2f(h1));
    const unsigned short l2 = b16(v.z - b2f(h2));
    const unsigned short l3 = b16(v.w - b2f(h3));
    ((ushort4*)hi)[i] = make_ushort4(h0, h1, h2, h3);
    ((ushort4*)lo)[i] = make_ushort4(l0, l1, l2, l3);
}

// ---------------------------------------------------------------- transpose + split: W[K,N] -> WT hi/lo [N,K]
__global__ __launch_bounds__(256) void k_splitT(const float* __restrict__ W,
                                                unsigned short* __restrict__ Thi,
                                                unsigned short* __restrict__ Tlo,
                                                int K, int N) {
    __shared__ float t[32][33];
    const int tx = threadIdx.x & 31, ty = threadIdx.x >> 5;   // 32 x 8
    const int n0 = blockIdx.x * 32, k0 = blockIdx.y * 32;
#pragma unroll
    for (int i = 0; i < 4; ++i)
        t[ty + i * 8][tx] = W[(size_t)(k0 + ty + i * 8) * N + n0 + tx];
    __syncthreads();
#pragma unroll
    for (int i = 0; i < 4; ++i) {
        const int n = n0 + ty + i * 8, k = k0 + tx;
        const float v = t[tx][ty + i * 8];
        const unsigned short h = b16(v);
        Thi[(size_t)n * K + k] = h;
        Tlo[(size_t)n * K + k] = b16(v - b2f(h));
    }
}

// ---------------------------------------------------------------- MFMA GEMM (split-bf16, 3-term)
// Tile 128(m) x 64(n), 4 waves of 64x32. A reg-staged (f32 -> selu? -> split ->
// swizzled ds_write); B via gload_lds (linear dest + SWZ source); reads SWZ'd.
// OUT_SPLIT=false: out = acc + bias (f32, gemm1 -> h).
// OUT_SPLIT=true : v = acc + bias + res; emit split bf16 hi/lo + rn2 atomics (gemm2).
template<int KTOT, bool OUT_SPLIT>
__global__ __launch_bounds__(256) void k_gemm(const float* __restrict__ A,
                                              const unsigned short* __restrict__ BThi,
                                              const unsigned short* __restrict__ BTlo,
                                              const float* __restrict__ bias,
                                              const float* __restrict__ res,
                                              float* __restrict__ outF,
                                              unsigned short* __restrict__ outHi,
                                              unsigned short* __restrict__ outLo,
                                              float* __restrict__ rn2) {
    __shared__ __align__(16) unsigned char smem[24576];   // AH 8K | AL 8K | BH 4K | BL 4K
    const int tid = threadIdx.x;
    const int wave = tid >> 6, lane = tid & 63;
    const int l15 = lane & 15, l4 = lane >> 4;
    const int m0 = blockIdx.x * 128, n0 = blockIdx.y * 64;
    const int wm0 = (wave >> 1) * 64, wn0 = (wave & 1) * 32;

    // B staging source offset (4KB tile, one round: chunk p = tid*16)
    const unsigned LB = SWZ((unsigned)tid * 16u);
    const int soffB = (int)(LB >> 6) * KTOT + (int)((LB >> 4) & 3) * 8;

    // fragment read offsets (mi/ni stride +1024)
    const unsigned ra0 = SWZ((unsigned)((wm0 + l15) * 64 + l4 * 16));
    const unsigned rb0 = SWZ((unsigned)((wn0 + l15) * 64 + l4 * 16));

    f32x4 acc[4][2];
#pragma unroll
    for (int a = 0; a < 4; ++a)
#pragma unroll
        for (int b = 0; b < 2; ++b) acc[a][b] = (f32x4)(0.f);

    for (int k0 = 0; k0 < KTOT; k0 += 32) {
        __syncthreads();
        // B: global_load_lds, linear dest (wave w covers bytes [w*1024,(w+1)*1024))
        GLOAD16(BThi + (size_t)n0 * KTOT + k0 + soffB, smem + 16384 + wave * 1024);
        GLOAD16(BTlo + (size_t)n0 * KTOT + k0 + soffB, smem + 20480 + wave * 1024);
        // A: reg-stage f32 -> (selu) -> split -> ds_write at SWZ(linear)
#pragma unroll
        for (int r = 0; r < 2; ++r) {
            const unsigned g = (unsigned)(tid + r * 256) * 16u;   // byte in [128][64B]
            const int grow = (int)(g >> 6), gel = (int)((g >> 4) & 3) * 8;
            const float4 v0 = *(const float4*)(A + (size_t)(m0 + grow) * KTOT + k0 + gel);
            const float4 v1 = *(const float4*)(A + (size_t)(m0 + grow) * KTOT + k0 + gel + 4);
            float s[8] = {v0.x, v0.y, v0.z, v0.w, v1.x, v1.y, v1.z, v1.w};
            u16x8 hv, lv;
#pragma unroll
            for (int j = 0; j < 8; ++j) {
                const float sv = OUT_SPLIT ? selu_f(s[j]) : s[j];
                const unsigned short hb = b16(sv);
                hv[j] = hb;
                lv[j] = b16(sv - b2f(hb));
            }
            const unsigned d = SWZ(g);
            *(u16x8*)(smem + d) = hv;
            *(u16x8*)(smem + 8192 + d) = lv;
        }
        __syncthreads();

        bf16x8 bh[2], bl[2];
#pragma unroll
        for (int ni = 0; ni < 2; ++ni) {
            bh[ni] = *(const bf16x8*)(smem + 16384 + rb0 + ni * 1024);
            bl[ni] = *(const bf16x8*)(smem + 20480 + rb0 + ni * 1024);
        }
#pragma unroll
        for (int mi = 0; mi < 4; ++mi) {
            const bf16x8 ah = *(const bf16x8*)(smem + ra0 + mi * 1024);
            const bf16x8 al = *(const bf16x8*)(smem + 8192 + ra0 + mi * 1024);
#pragma unroll
            for (int ni = 0; ni < 2; ++ni) {
                acc[mi][ni] = __builtin_amdgcn_mfma_f32_16x16x32_bf16(ah, bh[ni], acc[mi][ni], 0, 0, 0);
                acc[mi][ni] = __builtin_amdgcn_mfma_f32_16x16x32_bf16(ah, bl[ni], acc[mi][ni], 0, 0, 0);
                acc[mi][ni] = __builtin_amdgcn_mfma_f32_16x16x32_bf16(al, bh[ni], acc[mi][ni], 0, 0, 0);
            }
        }
    }
    // epilogue: C layout col = lane&15, row = (lane>>4)*4 + reg
#pragma unroll
    for (int mi = 0; mi < 4; ++mi)
#pragma unroll
        for (int rr = 0; rr < 4; ++rr) {
            const int m = m0 + wm0 + mi * 16 + l4 * 4 + rr;
            float s2 = 0.f;
#pragma unroll
            for (int ni = 0; ni < 2; ++ni) {
                const int n = n0 + wn0 + ni * 16 + l15;
                float v = acc[mi][ni][rr] + bias[n];
                if constexpr (OUT_SPLIT) {
                    v += res[(size_t)m * DIM + n];
                    const unsigned short hb = b16(v);
                    outHi[(size_t)m * DIM + n] = hb;
                    outLo[(size_t)m * DIM + n] = b16(v - b2f(hb));
                    s2 = fmaf(v, v, s2);
                } else {
                    outF[(size_t)m * DIM + n] = v;
                }
            }
            if constexpr (OUT_SPLIT) {
#pragma unroll
                for (int o = 1; o < 16; o <<= 1) s2 += __shfl_xor(s2, o);
                if (l15 == 0) atomicAdd(&rn2[m], s2);
            }
        }
}

// ---------------------------------------------------------------- MFMA distance + partial argmin
// Block: 128 tokens x 1024 codes (8 n-tiles of 128). 256 thr = 4 waves (2m x 2n),
// wave tile 64 tok x 64 codes (acc[4][4] = 64 regs -> NO spill, the round-7 bug).
// B (codes) in LDS dbuf 2x16KB = 32KB -> >=2 independent blocks/CU (desynced
// barriers hide each other's stage drain, m114). A (tokens) read directly
// global->register, SINGLE-buffered aH/aL[4] (32 regs): reloaded for the next
// iter AFTER the MFMA cluster issues (post-issue WAR on registers is safe),
// so the load latency overlaps barrier + next iter's ds_reads; A is L2-hot
// (256KB working set/block, re-read 8x). d2' = rn2[c] - 2*(xh.ch+xh.cl+xl.ch).
// Each col-half wave owns output slice = blockIdx.y*2 + (wave&1): 1 writer/slot.
__global__ __launch_bounds__(256, 2) void k_dist(const unsigned short* __restrict__ xh,
                                                 const unsigned short* __restrict__ xl,
                                                 const unsigned short* __restrict__ ch,
                                                 const unsigned short* __restrict__ cl,
                                                 const float* __restrict__ rn2,
                                                 float* __restrict__ pval,
                                                 int*   __restrict__ pidx) {
    __shared__ __align__(16) unsigned char smem[32768];   // {BH 8K | BL 8K} x 2
    const int tid  = threadIdx.x;
    const int wave = tid >> 6, lane = tid & 63;
    const int l15 = lane & 15, l4 = lane >> 4;
    const int m0   = blockIdx.x * 128;
    const int wm0  = (wave >> 1) * 64;     // token rows (2 m-waves)
    const int wn0  = (wave & 1) * 64;      // code cols (2 col-half waves)

    // B staging source offset: chunk p = tid*16 covers rows 0..63; round r adds
    // 64 rows (SWZ mask depends on row bits 1-3 only -> r/it-invariant)
    const unsigned LS = SWZ((unsigned)tid * 16u);
    const int soff0 = (int)(LS >> 6) * DIM + (int)((LS >> 4) & 3) * 8;

    // B fragment read offset (ni stride +1024; row bit 6 (wn0) mask-invariant)
    const unsigned rb0 = SWZ((unsigned)((wn0 + l15) * 64 + l4 * 16));

    // A per-lane base: token row m0+wm0+f*16+l15, k-slice l4*8 (16B contiguous)
    const unsigned short* xhb = xh + (size_t)(m0 + wm0 + l15) * DIM + l4 * 8;
    const unsigned short* xlb = xl + (size_t)(m0 + wm0 + l15) * DIM + l4 * 8;

    const int cbase = blockIdx.y * (CSIZE / NSLICE);
    constexpr int NT   = (CSIZE / NSLICE) / 128;   // 8 n-tiles
    constexpr int TOTI = NT * 16;                  // 128 K-step iterations

    auto stageB = [&](int it, unsigned bufbase) {
        const size_t cb0 = (size_t)(cbase + (it >> 4) * 128) * DIM + (it & 15) * 32 + soff0;
#pragma unroll
        for (int r = 0; r < 2; ++r) {
            GLOAD16(ch + cb0 + r * 64 * DIM, smem + bufbase + 0    + r * 4096 + wave * 1024);
            GLOAD16(cl + cb0 + r * 64 * DIM, smem + bufbase + 8192 + r * 4096 + wave * 1024);
        }
    };

    bf16x8 aH[4], aL[4];
    auto loadA = [&](int ks16) {            // ks16 = K-step within the 512-dim
        const int k0 = ks16 * 32;
#pragma unroll
        for (int f = 0; f < 4; ++f) {
            aH[f] = *(const bf16x8*)(xhb + (size_t)f * 16 * DIM + k0);
            aL[f] = *(const bf16x8*)(xlb + (size_t)f * 16 * DIM + k0);
        }
    };

    float bestv[4][4];
    int   besti[4][4];
#pragma unroll
    for (int a = 0; a < 4; ++a)
#pragma unroll
        for (int b = 0; b < 4; ++b) { bestv[a][b] = 3.0e38f; besti[a][b] = 0; }

    // prologue
    stageB(0, 0u);
    loadA(0);
    __syncthreads();
    unsigned cur = 0;

    for (int nt = 0; nt < NT; ++nt) {
        f32x4 acc[4][4];
#pragma unroll
        for (int a = 0; a < 4; ++a)
#pragma unroll
            for (int b = 0; b < 4; ++b) acc[a][b] = (f32x4)(0.f);

        for (int ks = 0; ks < 16; ++ks) {
            const int it = nt * 16 + ks;
            if (it + 1 < TOTI) stageB(it + 1, (cur ^ 1u) * 16384u);

            const unsigned char* base = smem + cur * 16384u;
            __builtin_amdgcn_s_setprio(1);
#pragma unroll
            for (int ni = 0; ni < 4; ++ni) {
                const bf16x8 bh = *(const bf16x8*)(base + rb0 + ni * 1024);
                const bf16x8 bl = *(const bf16x8*)(base + 8192 + rb0 + ni * 1024);
#pragma unroll
                for (int mi = 0; mi < 4; ++mi) {
                    acc[mi][ni] = __builtin_amdgcn_mfma_f32_16x16x32_bf16(aH[mi], bh, acc[mi][ni], 0, 0, 0);
                    acc[mi][ni] = __builtin_amdgcn_mfma_f32_16x16x32_bf16(aH[mi], bl, acc[mi][ni], 0, 0, 0);
                    acc[mi][ni] = __builtin_amdgcn_mfma_f32_16x16x32_bf16(aL[mi], bh, acc[mi][ni], 0, 0, 0);
                }
            }
            __builtin_amdgcn_s_setprio(0);
            // reload A for next iter AFTER the MFMA cluster (same regs, WAR-safe)
            if (it + 1 < TOTI) loadA((ks + 1) & 15);
            __syncthreads();   // drains stage of it+1; buffer swap safe
            cur ^= 1u;
        }

        // fold this n-tile into per-lane running best (d2 minus ||x||^2 const)
        const int n0 = cbase + nt * 128;
#pragma unroll
        for (int ni = 0; ni < 4; ++ni) {
            const int n = n0 + wn0 + ni * 16 + l15;
            const float r = rn2[n];
#pragma unroll
            for (int mi = 0; mi < 4; ++mi)
#pragma unroll
                for (int rr = 0; rr < 4; ++rr) {
                    const float v = fmaf(-2.f, acc[mi][ni][rr], r);
                    if (v < bestv[mi][rr]) { bestv[mi][rr] = v; besti[mi][rr] = n; }
                }
        }
    }

    // reduce across 16 column-lanes; each col-half wave owns its slice
    const int slice = blockIdx.y * 2 + (wave & 1);
#pragma unroll
    for (int mi = 0; mi < 4; ++mi)
#pragma unroll
        for (int rr = 0; rr < 4; ++rr) {
            float v = bestv[mi][rr];
            int   id = besti[mi][rr];
#pragma unroll
            for (int o = 1; o < 16; o <<= 1) {
                const float ov = __shfl_xor(v, o);
                const int   oid = __shfl_xor(id, o);
                if (ov < v || (ov == v && oid < id)) { v = ov; id = oid; }
            }
            if (l15 == 0) {
                const int m = m0 + wm0 + mi * 16 + l4 * 4 + rr;
                pval[(size_t)slice * NTOK + m] = v;
                pidx[(size_t)slice * NTOK + m] = id;
            }
        }
}

// ---------------------------------------------------------------- epilogue: argmin, gather(reconstruct), rotate, loss
// 4 tokens per block, one wave per token. Loss into 64 distributed slots.
__global__ __launch_bounds__(256) void k_epi(const float* __restrict__ x,
                                             const unsigned short* __restrict__ chi,
                                             const unsigned short* __restrict__ clo,
                                             const float* __restrict__ pval,
                                             const int*   __restrict__ pidx,
                                             float* __restrict__ out_q,
                                             float* __restrict__ out_idx,
                                             float* __restrict__ lossacc) {
    const int wave = threadIdx.x >> 6, lane = threadIdx.x & 63;
    const int t = blockIdx.x * 4 + wave;

    float v = 3.0e38f; int id = 0;
    if (lane < NSLICE2) {
        v  = pval[(size_t)lane * NTOK + t];
        id = pidx[(size_t)lane * NTOK + t];
    }
#pragma unroll
    for (int o = 1; o < 16; o <<= 1) {
        const float ov = __shfl_xor(v, o);
        const int   oid = __shfl_xor(id, o);
        if (ov < v || (ov == v && oid < id)) { v = ov; id = oid; }
    }
    id = __shfl(id, 0);

    const float4* xp = (const float4*)(x + (size_t)t * DIM);
    const float4 xv0 = xp[lane * 2];
    const float4 xv1 = xp[lane * 2 + 1];
    const u16x8 hv = *(const u16x8*)(chi + (size_t)id * DIM + lane * 8);
    const u16x8 lv = *(const u16x8*)(clo + (size_t)id * DIM + lane * 8);
    float q[8], xs[8] = {xv0.x, xv0.y, xv0.z, xv0.w, xv1.x, xv1.y, xv1.z, xv1.w};
#pragma unroll
    for (int j = 0; j < 8; ++j) q[j] = b2f(hv[j]) + b2f(lv[j]);

    float p0 = 0.f, p1 = 0.f, p2 = 0.f;
#pragma unroll
    for (int j = 0; j < 8; ++j) {
        p0 = fmaf(xs[j], xs[j], p0);
        p1 = fmaf(q[j], q[j], p1);
        p2 = fmaf(xs[j], q[j], p2);
    }
#pragma unroll
    for (int o = 1; o < 64; o <<= 1) {
        p0 += __shfl_xor(p0, o);
        p1 += __shfl_xor(p1, o);
        p2 += __shfl_xor(p2, o);
    }
    const float sx2 = p0, sq2 = p1, sxq = p2;

    const float ns  = sqrtf(sx2);
    const float nt  = sqrtf(sq2);
    const float nsc = fmaxf(ns, EPSV);
    const float ntc = fmaxf(nt, EPSV);
    const float xu  = sx2 / nsc;
    const float xqh = sxq / ntc;
    const float xw0 = xu + xqh;
    const float w0n2 = sx2 / (nsc * nsc) + 2.f * sxq / (nsc * ntc) + sq2 / (ntc * ntc);
    const float w0nc = fmaxf(sqrtf(w0n2), EPSV);
    const float coefW = 2.f * xw0 / (w0nc * w0nc);
    const float coefQ = 2.f * xu / ntc;
    const float scale = nt / nsc;
    const float cx = scale * (1.f - coefW / nsc);
    const float cq = scale * (coefQ - coefW / ntc);

    float4 ov0, ov1;
    ov0.x = cx * xs[0] + cq * q[0];  ov0.y = cx * xs[1] + cq * q[1];
    ov0.z = cx * xs[2] + cq * q[2];  ov0.w = cx * xs[3] + cq * q[3];
    ov1.x = cx * xs[4] + cq * q[4];  ov1.y = cx * xs[5] + cq * q[5];
    ov1.z = cx * xs[6] + cq * q[6];  ov1.w = cx * xs[7] + cq * q[7];
    ((float4*)(out_q + (size_t)t * DIM))[lane * 2]     = ov0;
    ((float4*)(out_q + (size_t)t * DIM))[lane * 2 + 1] = ov1;

    __shared__ float sew[4];
    if (lane == 0) {
        out_idx[t] = (float)id;
        sew[wave] = sx2 - 2.f * sxq + sq2;
    }
    __syncthreads();
    if (threadIdx.x == 0) {
        const float se = sew[0] + sew[1] + sew[2] + sew[3];
        atomicAdd(lossacc + (blockIdx.x & 63), se);
    }
}

// ---------------------------------------------------------------- launch
extern "C" void kernel_launch(void* const* d_in, const int* in_sizes, int n_in,
                              void* d_out, int out_size, void* d_ws, size_t ws_size,
                              hipStream_t stream) {
    const float* x  = (const float*)d_in[0];
    const float* cb = (const float*)d_in[1];
    const float* W1 = (const float*)d_in[2];
    const float* b1 = (const float*)d_in[3];
    const float* W2 = (const float*)d_in[4];
    const float* b2 = (const float*)d_in[5];

    char* ws = (char*)d_ws;
    float* h = (float*)ws;                                         // 16.78 MB (gemm1 out)
    unsigned short* chi = (unsigned short*)(h + (size_t)CSIZE * DIM);   // 8.39 MB
    unsigned short* clo = chi + (size_t)CSIZE * DIM;               // 8.39 MB
    unsigned short* W1Thi = clo + (size_t)CSIZE * DIM;
    unsigned short* W1Tlo = W1Thi + (size_t)DIM * CDIM;
    unsigned short* W2Thi = W1Tlo + (size_t)DIM * CDIM;
    unsigned short* W2Tlo = W2Thi + (size_t)DIM * DIM;
    float* rn2  = (float*)(W2Tlo + (size_t)DIM * DIM);             // 32 KB
    float* pval = rn2 + CSIZE;                                     // 16*NTOK f32
    int*   pidx = (int*)(pval + (size_t)NSLICE2 * NTOK);           // 16*NTOK i32
    float* lossacc = (float*)(pidx + (size_t)NSLICE2 * NTOK);      // 64 f32

    // x splits overlay d_out's out_q region (dead until k_epi writes it)
    unsigned short* xhi = (unsigned short*)d_out;
    unsigned short* xlo = xhi + (size_t)NTOK * DIM;

    float* out_q    = (float*)d_out;
    float* out_idx  = out_q + (size_t)NTOK * DIM;
    float* out_loss = out_idx + NTOK;

    k_init<<<(CSIZE + 255) / 256, 256, 0, stream>>>(rn2, lossacc);
    k_split<<<(NTOK * DIM / 4) / 256, 256, 0, stream>>>(x, xhi, xlo, NTOK * DIM / 4);
    k_splitT<<<dim3(DIM / 32, CDIM / 32), 256, 0, stream>>>(W1, W1Thi, W1Tlo, CDIM, DIM);
    k_splitT<<<dim3(DIM / 32, DIM / 32), 256, 0, stream>>>(W2, W2Thi, W2Tlo, DIM, DIM);
    k_gemm<CDIM, false><<<dim3(CSIZE / 128, DIM / 64), 256, 0, stream>>>(
        cb, W1Thi, W1Tlo, b1, nullptr, h, nullptr, nullptr, nullptr);
    k_gemm<DIM, true><<<dim3(CSIZE / 128, DIM / 64), 256, 0, stream>>>(
        h, W2Thi, W2Tlo, b2, h, nullptr, chi, clo, rn2);
    k_dist<<<dim3(NTOK / 128, NSLICE), 256, 0, stream>>>(xhi, xlo, chi, clo, rn2, pval, pidx);
    k_epi<<<NTOK / 4, 256, 0, stream>>>(x, chi, clo, pval, pidx, out_q, out_idx, lossacc);
    k_fin<<<1, 64, 0, stream>>>(lossacc, out_loss);
}